// Round 3
// baseline (222.491 us; speedup 1.0000x reference)
//
#include <hip/hip_runtime.h>

typedef __attribute__((ext_vector_type(8))) short short8;
typedef __attribute__((ext_vector_type(4))) float f32x4;
typedef __attribute__((ext_vector_type(4))) int i32x4;

#define HW 56
#define P_IMG 3136          // 56*56
#define XSTRIDE 802816      // 256*3136
#define OUT_C 256
#define K_TOT 1152
#define KT_N 18             // 1152/64
#define BM 64
#define NBLK 784            // 50176/64 = 784 = 8*98

__device__ __forceinline__ unsigned short f2bf_bits(float f) {
    unsigned u = __builtin_bit_cast(unsigned, f);
    return (unsigned short)((u + 0x7FFFu + ((u >> 16) & 1u)) >> 16);
}

// W prep: gw2[s][oc][j] = bf16( w[(s*8+j)*256 + oc] ), s in [0,144), j in [0,8)
// -> lane fragment (slice s = kt*8+ks*4+lhi, row oc) is one contiguous 16B load.
__global__ __launch_bounds__(256) void prep_w_kernel(const float* __restrict__ w,
                                                     unsigned short* __restrict__ gw) {
    int i = blockIdx.x * 256 + threadIdx.x;   // 36864 = 144*256
    int oc = i & 255;
    int s = i >> 8;                           // 0..143
    short8 pk;
    #pragma unroll
    for (int j = 0; j < 8; ++j)
        pk[j] = (short)f2bf_bits(w[(s * 8 + j) * 256 + oc]);   // coalesced over oc
    *(short8*)(gw + s * 2048 + oc * 8) = pk;
}

// idx prep: pack biased address delta (+57 so >=0) and (dh*3+dw) in bits 20..23
__global__ __launch_bounds__(256) void prep_idx_kernel(const int* __restrict__ idx,
                                                       int* __restrict__ didx) {
    int i = blockIdx.x * 256 + threadIdx.x;
    if (i < K_TOT) {
        int v = idx[i];
        int c = v / 9;
        int rr = v - c * 9;           // dh*3+dw
        int dh = rr / 3;
        int dw = rr - dh * 3;
        int delta_b = c * P_IMG + (dh - 1) * HW + (dw - 1) + 57;
        didx[i] = delta_b | (rr << 20);
    }
}

__global__ __launch_bounds__(512, 4) void mconv_mfma(
        const float* __restrict__ x,
        const unsigned short* __restrict__ gw,
        const int* __restrict__ didx,
        float* __restrict__ out) {
    __shared__ __attribute__((aligned(16))) char smem[16384];
    char* const A0 = smem;              // [64 m][64 k] bf16, XOR-swizzled rows
    char* const A1 = smem + 8192;

    const int tid = threadIdx.x;
    const int wv  = tid >> 6;
    const int ln  = tid & 63;
    const int lhi = ln >> 4;
    const int llo = ln & 15;
    const int oc0 = (wv >> 1) * 64;     // wave tile: 64 oc x 32 m
    const int mw0 = (wv & 1) * 32;

    const int bid = blockIdx.x;
    const int m0 = ((bid & 7) * 98 + (bid >> 3)) * BM;   // XCD swizzle, 784=8*98

    // A-staging coords: thread -> (row sr, k-octet sq)
    const int sr = tid >> 3;            // 0..63
    const int sq = tid & 7;             // 0..7
    const int mrow = m0 + sr;
    const int nimg = mrow / P_IMG;
    const int p = mrow - nimg * P_IMG;
    const int oh = p / HW;
    const int ow = p - oh * HW;
    const int gbase = nimg * XSTRIDE + p - 57;   // -57 cancels delta bias
    const int ohm1 = oh - 1, owm1 = ow - 1;

    // 9-bit pad-validity LUT over (dh,dw)
    unsigned oklut = 0;
    #pragma unroll
    for (int dh = 0; dh < 3; ++dh)
        #pragma unroll
        for (int dw = 0; dw < 3; ++dw) {
            bool okh = (unsigned)(ohm1 + dh) < (unsigned)HW;
            bool okw = (unsigned)(owm1 + dw) < (unsigned)HW;
            if (okh && okw) oklut |= (1u << (dh * 3 + dw));
        }

    const int swz = (sr & 7) << 4;
    char* const rowp0 = A0 + sr * 128;
    char* const rowp1 = A1 + sr * 128;

    // ---- prologue: stage tile 0 ----
    {
        float tv[8];
        unsigned okm = 0;
        const int kbase = sq * 8;
        i32x4 d0 = *(const i32x4*)(didx + kbase);
        i32x4 d1 = *(const i32x4*)(didx + kbase + 4);
        int vv[8] = { d0.x, d0.y, d0.z, d0.w, d1.x, d1.y, d1.z, d1.w };
        #pragma unroll
        for (int j = 0; j < 8; ++j) {
            int v = vv[j];
            int addr = gbase + (v & 0xFFFFF);
            unsigned ok = (oklut >> (v >> 20)) & 1u;
            tv[j] = x[ok ? addr : 0];
            okm |= ok << j;
        }
        short8 pk;
        #pragma unroll
        for (int j = 0; j < 8; ++j)
            pk[j] = (short)(((okm >> j) & 1u) ? f2bf_bits(tv[j]) : (unsigned short)0);
        *(short8*)(rowp0 + ((sq * 16) ^ swz)) = pk;
    }
    __syncthreads();

    f32x4 acc[4][2] = {};   // [ni][mi], D[oc][m]

    for (int kt = 0; kt < KT_N; ++kt) {
        char* const Ac = (kt & 1) ? A1 : A0;
        char* const rowpn = (kt & 1) ? rowp0 : rowp1;

        float tv[8];
        unsigned okm = 0;
        const bool do_stage = (kt + 1 < KT_N);
        if (do_stage) {
            // issue gather loads for next tile (results consumed after MFMA)
            const int kbase = (kt + 1) * 64 + sq * 8;
            i32x4 d0 = *(const i32x4*)(didx + kbase);
            i32x4 d1 = *(const i32x4*)(didx + kbase + 4);
            int vv[8] = { d0.x, d0.y, d0.z, d0.w, d1.x, d1.y, d1.z, d1.w };
            #pragma unroll
            for (int j = 0; j < 8; ++j) {
                int v = vv[j];
                int addr = gbase + (v & 0xFFFFF);
                unsigned ok = (oklut >> (v >> 20)) & 1u;
                tv[j] = x[ok ? addr : 0];
                okm |= ok << j;
            }
        }
        __builtin_amdgcn_sched_barrier(0);  // keep gather issue above the MFMA block

        // compute current tile: D[oc][m] += W-frag (global/L2) * A-frag (LDS)
        #pragma unroll
        for (int ks = 0; ks < 2; ++ks) {
            short8 wf[4], af[2];
            #pragma unroll
            for (int i = 0; i < 4; ++i) {
                const int row = oc0 + i * 16 + llo;
                wf[i] = *(const short8*)(gw + (kt * 8 + ks * 4 + lhi) * 2048 + row * 8);
            }
            #pragma unroll
            for (int i = 0; i < 2; ++i) {
                const int row = mw0 + i * 16 + llo;
                af[i] = *(const short8*)(Ac + row * 128 + ((ks * 64 + lhi * 16) ^ ((row & 7) << 4)));
            }
            #pragma unroll
            for (int ni = 0; ni < 4; ++ni)
                #pragma unroll
                for (int mi = 0; mi < 2; ++mi)
                    acc[ni][mi] = __builtin_amdgcn_mfma_f32_16x16x32_bf16(wf[ni], af[mi], acc[ni][mi], 0, 0, 0);
        }

        if (do_stage) {
            // late write: select/convert/ds_write (loads hid under MFMA)
            short8 pk;
            #pragma unroll
            for (int j = 0; j < 8; ++j)
                pk[j] = (short)(((okm >> j) & 1u) ? f2bf_bits(tv[j]) : (unsigned short)0);
            *(short8*)(rowpn + ((sq * 16) ^ swz)) = pk;
        }
        __syncthreads();
    }

    // ---- epilogue: D[oc][m] -> out[n][oc][p], m contiguous across lanes ----
    #pragma unroll
    for (int mi = 0; mi < 2; ++mi) {
        const int mg = m0 + mw0 + mi * 16 + llo;
        const int n = mg / P_IMG;
        const int pp = mg - n * P_IMG;
        float* ob = out + n * XSTRIDE + pp;
        #pragma unroll
        for (int ni = 0; ni < 4; ++ni) {
            const int ocb = (oc0 + ni * 16 + lhi * 4) * P_IMG;
            #pragma unroll
            for (int j = 0; j < 4; ++j)
                ob[ocb + j * P_IMG] = acc[ni][mi][j];
        }
    }
}

extern "C" void kernel_launch(void* const* d_in, const int* in_sizes, int n_in,
                              void* d_out, int out_size, void* d_ws, size_t ws_size,
                              hipStream_t stream) {
    const float* x  = (const float*)d_in[0];
    const float* w  = (const float*)d_in[1];
    const int* idx  = (const int*)d_in[2];
    float* out = (float*)d_out;

    unsigned short* gw = (unsigned short*)d_ws;                    // 589824 B
    int* didx = (int*)((char*)d_ws + K_TOT * OUT_C * 2);           // 4608 B

    prep_w_kernel<<<dim3(144), dim3(256), 0, stream>>>(w, gw);
    prep_idx_kernel<<<dim3(5), dim3(256), 0, stream>>>(idx, didx);
    mconv_mfma<<<dim3(NBLK), dim3(512), 0, stream>>>(x, gw, didx, out);
}

// Round 13
// 177.697 us; speedup vs baseline: 1.2521x; 1.2521x over previous
//
#include <hip/hip_runtime.h>

typedef __attribute__((ext_vector_type(8))) short short8;
typedef __attribute__((ext_vector_type(4))) short s16x4;
typedef __attribute__((ext_vector_type(4))) float f32x4;
typedef __attribute__((ext_vector_type(4))) int i32x4;

typedef __attribute__((address_space(1))) const unsigned int gas_u32;
typedef __attribute__((address_space(3))) unsigned int las_u32;

#define HW 56
#define P_IMG 3136          // 56*56
#define XSTRIDE 802816      // 256*3136
#define OUT_C 256
#define K_TOT 1152
#define NSTEP 36            // 1152/32
#define BM 64
#define NBLK 784            // 50176/64 = 8*98

// LDS map (bytes): W 3x16384 @0 ; A 3x4096 @49152 ; didx 4608 @61440 ; total 66048
#define WOFF0 0
#define AOFF  49152
#define DOFF  61440

__device__ __forceinline__ unsigned short f2bf_bits(float f) {
    unsigned u = __builtin_bit_cast(unsigned, f);
    return (unsigned short)((u + 0x7FFFu + ((u >> 16) & 1u)) >> 16);
}

// W prep, k-octet subtiled: gw[t][oct][oc][j] = bf16( w[(t*32 + oct*8 + j)*256 + oc] )
// 16B block per (oct,oc) -> LDS fragment reads are 256B-contiguous per 16 lanes
// (conflict-free); global_load_lds stages it as a linear byte copy.
__global__ __launch_bounds__(256) void prep_w_kernel(const float* __restrict__ w,
                                                     unsigned short* __restrict__ gw) {
    int i = blockIdx.x * 256 + threadIdx.x;   // 9216 = 36*256
    int oc = i & 255;
    int t = i >> 8;
    #pragma unroll
    for (int oct = 0; oct < 4; ++oct) {
        short8 v;
        #pragma unroll
        for (int j = 0; j < 8; ++j)
            v[j] = (short)f2bf_bits(w[(t * 32 + oct * 8 + j) * 256 + oc]);  // coalesced over oc
        *(short8*)(gw + t * 8192 + oct * 2048 + oc * 8) = v;
    }
}

// didx: biased address delta (+57) | (dh*3+dw)<<20 ; also zero the pad word.
__global__ __launch_bounds__(256) void prep_idx_kernel(const int* __restrict__ idx,
                                                       int* __restrict__ didx,
                                                       float* __restrict__ zw) {
    int i = blockIdx.x * 256 + threadIdx.x;
    if (i == 0) zw[0] = 0.0f;            // ws is re-poisoned 0xAA each call
    if (i < K_TOT) {
        int v = idx[i];
        int c = v / 9;
        int rr = v - c * 9;
        int dh = rr / 3;
        int dw = rr - dh * 3;
        int delta_b = c * P_IMG + (dh - 1) * HW + (dw - 1) + 57;
        didx[i] = delta_b | (rr << 20);
    }
}

__global__ __launch_bounds__(512, 4) void mconv_mfma(
        const float* __restrict__ x,
        const unsigned short* __restrict__ gw,
        const int* __restrict__ didx_g,
        const float* __restrict__ zw,
        float* __restrict__ out) {
    __shared__ __attribute__((aligned(16))) char smem[66048];

    const int tid = threadIdx.x;
    const int wv  = tid >> 6;
    const int ln  = tid & 63;
    const int lhi = ln >> 4;
    const int llo = ln & 15;
    const int oc0 = (wv >> 1) * 64;     // wave tile: 64 oc x 32 m
    const int mw0 = (wv & 1) * 32;

    const int bid = blockIdx.x;
    const int m0 = ((bid & 7) * 98 + (bid >> 3)) * BM;   // XCD swizzle, 784=8*98

    // gather slot: row sr (64 rows), k-quad sq (k = sq*4+j)
    const int sr = tid >> 3;
    const int sq = tid & 7;
    const int mrow = m0 + sr;
    const int nimg = mrow / P_IMG;
    const int p = mrow - nimg * P_IMG;
    const int oh = p / HW;
    const int ow = p - oh * HW;
    const int gbase = nimg * XSTRIDE + p - 57;   // -57 cancels delta bias
    unsigned oklut = 0;
    #pragma unroll
    for (int dh = 0; dh < 3; ++dh)
        #pragma unroll
        for (int dw = 0; dw < 3; ++dw)
            if ((unsigned)(oh - 1 + dh) < (unsigned)HW && (unsigned)(ow - 1 + dw) < (unsigned)HW)
                oklut |= 1u << (dh * 3 + dw);

    const int* didx_l = (const int*)(smem + DOFF);
    f32x4 acc[4][2] = {};
    float tv0[4], tv1[4];

    // A-tile byte offsets (k-octet subtiled [4 oct][64 m][16B]):
    const int a_wr_off = (sq >> 1) * 1024 + sr * 16 + (sq & 1) * 8;

    // ---------- helpers ----------
    auto ISSUE_G2 = [&](i32x4 d, float* tv) {
        int vv[4] = { d.x, d.y, d.z, d.w };
        #pragma unroll
        for (int j = 0; j < 4; ++j) {
            int v = vv[j];
            const float* ptr = ((oklut >> (v >> 20)) & 1u) ? (x + gbase + (v & 0xFFFFF)) : zw;
            tv[j] = *ptr;                                   // global_load_dword
        }
    };
    auto ISSUE_G = [&](int s2, float* tv) {
        ISSUE_G2(*(const i32x4*)(didx_l + s2 * 32 + sq * 4), tv);
    };
    auto ISSUE_W = [&](int s2, int wOff) {
        const char* gsrc = (const char*)gw + s2 * 16384;
        #pragma unroll
        for (int q = 0; q < 2; ++q) {
            int slot = q * 8 + wv;
            __builtin_amdgcn_global_load_lds((gas_u32*)(gsrc + slot * 1024 + ln * 16),
                                             (las_u32*)(smem + wOff + slot * 1024), 16, 0, 0);
        }
    };
    auto COMPUTE = [&](int aOff, int wOff) {
        short8 wf[4], af[2];
        #pragma unroll
        for (int i = 0; i < 4; ++i)
            wf[i] = *(const short8*)(smem + wOff + lhi * 4096 + (oc0 + i * 16 + llo) * 16);
        #pragma unroll
        for (int i = 0; i < 2; ++i)
            af[i] = *(const short8*)(smem + aOff + lhi * 1024 + (mw0 + i * 16 + llo) * 16);
        #pragma unroll
        for (int ni = 0; ni < 4; ++ni)
            #pragma unroll
            for (int mi = 0; mi < 2; ++mi)
                acc[ni][mi] = __builtin_amdgcn_mfma_f32_16x16x32_bf16(wf[ni], af[mi], acc[ni][mi], 0, 0, 0);
    };
    auto CVT_WR = [&](const float* tv, int aOff) {
        s16x4 pk;
        #pragma unroll
        for (int j = 0; j < 4; ++j) pk[j] = (short)f2bf_bits(tv[j]);
        *(s16x4*)(smem + aOff + a_wr_off) = pk;
    };
#define WAITV6 { asm volatile("s_waitcnt vmcnt(6)" ::: "memory"); __builtin_amdgcn_sched_barrier(0); }
#define WAITV0 { asm volatile("s_waitcnt vmcnt(0)" ::: "memory"); __builtin_amdgcn_sched_barrier(0); }
#define WAITL0 { asm volatile("s_waitcnt lgkmcnt(0)" ::: "memory"); __builtin_amdgcn_sched_barrier(0); }
#define BAR    __builtin_amdgcn_s_barrier()
#define ROT()  { int t_ = aC; aC = aN; aN = aN2; aN2 = t_; t_ = wC; wC = wN; wN = wN2; wN2 = t_; }

    // ---------- prologue ----------
    // didx -> LDS (18 wave-chunks of 256B)
    #pragma unroll
    for (int q = 0; q < 3; ++q) {
        int off = (q * 8 + wv) * 256;
        if (off < 4608)
            __builtin_amdgcn_global_load_lds((gas_u32*)((const char*)didx_g + off + ln * 4),
                                             (las_u32*)(smem + DOFF + off), 4, 0, 0);
    }
    i32x4 dr0 = *(const i32x4*)(didx_g + sq * 4);          // step 0 descriptors
    i32x4 dr1 = *(const i32x4*)(didx_g + 32 + sq * 4);     // step 1 descriptors
    WAITV0; BAR;

    int aC = AOFF, aN = AOFF + 4096, aN2 = AOFF + 8192;
    int wC = WOFF0, wN = WOFF0 + 16384, wN2 = WOFF0 + 32768;

    ISSUE_G2(dr0, tv0); ISSUE_W(0, wC);
    ISSUE_G2(dr1, tv1); ISSUE_W(1, wN);
    WAITV6;                      // Batch(0) done; Batch(1) in flight
    CVT_WR(tv0, aC);             // A[0]
    WAITL0; BAR;

    // ---------- main loop: steps 0..33 (17 pairs) ----------
    for (int pp = 0; pp < 17; ++pp) {
        const int s0 = 2 * pp;
        // step s0 (even)
        ISSUE_G(s0 + 2, tv0); ISSUE_W(s0 + 2, wN2);
        COMPUTE(aC, wC);
        WAITV6;                  // retire Batch(s0+1): gathers + W glds
        CVT_WR(tv1, aN);         // A[s0+1]
        WAITL0; BAR;
        ROT();
        // step s0+1 (odd)
        ISSUE_G(s0 + 3, tv1); ISSUE_W(s0 + 3, wN2);
        COMPUTE(aC, wC);
        WAITV6;
        CVT_WR(tv0, aN);
        WAITL0; BAR;
        ROT();
    }

    // ---------- tail ----------
    // step 34: nothing left to issue
    COMPUTE(aC, wC);
    WAITV0;                      // retire Batch(35) fully
    CVT_WR(tv1, aN);             // A[35]
    WAITL0; BAR;
    ROT();
    // step 35
    COMPUTE(aC, wC);

    // ---------- epilogue: D[oc][m] -> out[n][oc][p] ----------
    #pragma unroll
    for (int mi = 0; mi < 2; ++mi) {
        const int mg = m0 + mw0 + mi * 16 + llo;
        const int n = mg / P_IMG;
        const int ppx = mg - n * P_IMG;
        float* ob = out + n * XSTRIDE + ppx;
        #pragma unroll
        for (int ni = 0; ni < 4; ++ni) {
            const int ocb = (oc0 + ni * 16 + lhi * 4) * P_IMG;
            #pragma unroll
            for (int j = 0; j < 4; ++j)
                ob[ocb + j * P_IMG] = acc[ni][mi][j];
        }
    }
#undef WAITV6
#undef WAITV0
#undef WAITL0
#undef BAR
#undef ROT
}

extern "C" void kernel_launch(void* const* d_in, const int* in_sizes, int n_in,
                              void* d_out, int out_size, void* d_ws, size_t ws_size,
                              hipStream_t stream) {
    const float* x  = (const float*)d_in[0];
    const float* w  = (const float*)d_in[1];
    const int* idx  = (const int*)d_in[2];
    float* out = (float*)d_out;

    unsigned short* gw = (unsigned short*)d_ws;                      // 589824 B
    int* didx  = (int*)((char*)d_ws + 589824);                       // 4608 B
    float* zw  = (float*)((char*)d_ws + 594432);                     // 4 B

    prep_w_kernel<<<dim3(36), dim3(256), 0, stream>>>(w, gw);
    prep_idx_kernel<<<dim3(5), dim3(256), 0, stream>>>(idx, didx, zw);
    mconv_mfma<<<dim3(NBLK), dim3(512), 0, stream>>>(x, gw, didx, zw, out);
}